// Round 14
// baseline (24.489 us; speedup 1.0000x reference)
//
#include <hip/hip_runtime.h>

// NodeCycleFeatures via MFMA: R10 structure + cross-batch register prefetch.
// Grid 1024 blocks x 256 threads; each block processes 2 batches SEQUENTIALLY
// reusing the same LDS buffers (17.4 KB), with batch m+1's E (8 float4/thread)
// prefetched into registers during batch m's compute. Overlaps the E-stream
// with MFMA/VALU work without halving LDS occupancy (R11's mistake).
// Wave w owns MFMA tile (R,C)=(w>>1,w&1) of k2=A@A and k3=k2@A
// (v_mfma_f32_32x32x16_bf16; all values integer-exact in bf16/u16/f32).
// C/D layout (verified R8-R13): col=lane&31, row=(reg&3)+8*(reg>>2)+4*(lane>>5).
// k2/k3 stored col-major (== row-major by symmetry), 16B-block XOR swizzle.

typedef __attribute__((ext_vector_type(8))) short bf16x8;
typedef __attribute__((ext_vector_type(16))) float f32x16;

constexpr int BATCH = 2048;
constexpr int NN = 64;

__device__ __forceinline__ bf16x8 frag_ld(const unsigned short* buf, int row, int kb2) {
  const int idx = row * 64 + ((kb2 ^ (row & 7)) << 3);  // 16B-block swizzle
  const uint4 v = *reinterpret_cast<const uint4*>(buf + idx);
  union { uint4 u; bf16x8 b; } cv; cv.u = v; return cv.b;
}

__device__ __forceinline__ void write_A(unsigned short* bA, uint2 mm, int w, int lane) {
  const unsigned word = (w < 2) ? mm.x : mm.y;
  const unsigned bits16 = (word >> (16 * (w & 1))) & 0xffffu;
  #pragma unroll
  for (int e = 0; e < 2; ++e) {
    const int bq = 2 * w + e;
    unsigned wv[4];
    #pragma unroll
    for (int p2 = 0; p2 < 4; ++p2) {
      const int c0 = e * 8 + p2 * 2;
      wv[p2] = (((bits16 >> c0) & 1u) ? 0x3F80u : 0u)
             | (((bits16 >> (c0 + 1)) & 1u) ? 0x3F800000u : 0u);
    }
    const int idx = lane * 64 + ((bq ^ (lane & 7)) << 3);
    *reinterpret_cast<uint4*>(&bA[idx]) = make_uint4(wv[0], wv[1], wv[2], wv[3]);
  }
}

__device__ __forceinline__ void pack_k2(unsigned short* bK2, const f32x16& acc,
                                        int R, int C, int c31, int h) {
  const int c = C * 32 + c31;
  #pragma unroll
  for (int g = 0; g < 4; ++g) {
    const unsigned w0 = (__float_as_uint(acc[4*g+1]) & 0xffff0000u) |
                        (__float_as_uint(acc[4*g+0]) >> 16);
    const unsigned w1 = (__float_as_uint(acc[4*g+3]) & 0xffff0000u) |
                        (__float_as_uint(acc[4*g+2]) >> 16);
    const int bb = (4 * R + g) ^ (c & 7);
    *reinterpret_cast<uint2*>(&bK2[c * 64 + bb * 8 + h * 4]) = make_uint2(w0, w1);
  }
}

__device__ __forceinline__ void pack_k3(unsigned short* bK3, const f32x16& d,
                                        int R, int C, int c31, int h) {
  const int c = C * 32 + c31;
  #pragma unroll
  for (int g = 0; g < 4; ++g) {
    const unsigned u0 = ((unsigned)d[4*g+0]) | (((unsigned)d[4*g+1]) << 16);
    const unsigned u1 = ((unsigned)d[4*g+2]) | (((unsigned)d[4*g+3]) << 16);
    const int bb = (4 * R + g) ^ (c & 7);
    *reinterpret_cast<uint2*>(&bK3[c * 64 + bb * 8 + h * 4]) = make_uint2(u0, u1);
  }
}

__device__ __forceinline__ void diag_c3(float* c3p, const f32x16& d,
                                        int R, int C, int c31, int h) {
  if (R == C) {
    const int dtarget = c31 - 4 * h;
    float c3d = 0.f;
    #pragma unroll
    for (int r = 0; r < 16; ++r) {
      const int rowbase = (r & 3) + 8 * (r >> 2);
      c3d += (rowbase == dtarget) ? d[r] : 0.f;
    }
    if (((c31 >> 2) & 1) == h) c3p[R * 32 + c31] = c3d;
  }
}

struct RP { float diag4, Ad, diag5, t3p, Atri, t1p, t8p; };

__device__ __forceinline__ RP rowpass(const unsigned short* bK2, const unsigned short* bK3,
                                      const float* c3p, uint2 mr, int rp_r, int rp_q) {
  RP o = {0.f, 0.f, 0.f, 0.f, 0.f, 0.f, 0.f};
  #pragma unroll
  for (int e = 0; e < 2; ++e) {
    const int bq = 2 * rp_q + e;
    const int idx = rp_r * 64 + ((bq ^ (rp_r & 7)) << 3);
    const uint4 vk2 = *reinterpret_cast<const uint4*>(&bK2[idx]);
    const uint4 vk3 = *reinterpret_cast<const uint4*>(&bK3[idx]);
    const float4 c3a = *reinterpret_cast<const float4*>(&c3p[bq * 8]);
    const float4 c3b = *reinterpret_cast<const float4*>(&c3p[bq * 8 + 4]);
    const unsigned wk2[4] = {vk2.x, vk2.y, vk2.z, vk2.w};
    const unsigned wk3[4] = {vk3.x, vk3.y, vk3.z, vk3.w};
    const float c3v[8] = {c3a.x, c3a.y, c3a.z, c3a.w, c3b.x, c3b.y, c3b.z, c3b.w};
    #pragma unroll
    for (int e2 = 0; e2 < 4; ++e2) {
      const int j0 = bq * 8 + 2 * e2;
      const float k2lo = __uint_as_float(wk2[e2] << 16);
      const float k2hi = __uint_as_float(wk2[e2] & 0xffff0000u);
      const float k3lo = (float)(wk3[e2] & 0xffffu);
      const float k3hi = (float)(wk3[e2] >> 16);
      o.diag4 = fmaf(k2lo, k2lo, fmaf(k2hi, k2hi, o.diag4));
      o.Ad += k2lo + k2hi;                               // (A@d)[r] = row-sum k2
      o.diag5 = fmaf(k2lo, k3lo, fmaf(k2hi, k3hi, o.diag5));
      o.t1p = fmaf(k3lo, k3lo, fmaf(k3hi, k3hi, o.t1p)); // -> trace(k6)
      o.t8p += k3lo + k3hi;                              // -> sum(k3)
      const unsigned b0 = (j0 < 32 ? (mr.x >> j0) : (mr.y >> (j0 - 32))) & 1u;
      const unsigned b1 = ((j0 + 1) < 32 ? (mr.x >> (j0 + 1)) : (mr.y >> (j0 + 1 - 32))) & 1u;
      o.t3p = fmaf(b0 ? k2lo : 0.f, k2lo, fmaf(b1 ? k2hi : 0.f, k2hi, o.t3p));
      o.Atri += (b0 ? c3v[2 * e2] : 0.f) + (b1 ? c3v[2 * e2 + 1] : 0.f);
    }
  }
  return o;
}

__global__ __launch_bounds__(256, 4) void node_cycle_kernel(
    const float4* __restrict__ E4,   // [B,N,N,2] floats viewed as float4
    const float* __restrict__ nmask, // [B,N]
    float* __restrict__ out)         // x: [B,N,3] then y: [B,4]
{
  const int tid = threadIdx.x;
  const int lane = tid & 63;
  const int w = tid >> 6;
  const int h = lane >> 5;
  const int c31 = lane & 31;
  const int R = w >> 1, C = w & 1;

  __shared__ unsigned short bufA[4096];   // A bf16; reused for k3 (u16)
  __shared__ unsigned short bufK2[4096];  // k2 bf16
  __shared__ unsigned short sl[4][64];    // 16-bit col-mask slices
  __shared__ uint2 rms[NN];
  __shared__ float c3sh[NN];
  __shared__ float4 gpart[4];

  // ---- Prologue: prefetch batch 2*blockIdx.x ----
  const size_t base0 = (size_t)(2 * blockIdx.x) * 2048;
  float4 pref[8];
  #pragma unroll
  for (int q = 0; q < 8; ++q)
    pref[q] = E4[base0 + w * 512 + q * 64 + lane];  // row=16w+2q+h, colpair=lane&31

  for (int m = 0; m < 2; ++m) {
    const int b = 2 * blockIdx.x + m;

    // ---- Mask slices from prefetched registers ----
    unsigned mA = 0u, mB = 0u;
    #pragma unroll
    for (int q = 0; q < 8; ++q) {
      const int bit = 2 * q + h;
      mA |= (unsigned)(pref[q].y > 0.5f) << bit;
      mB |= (unsigned)(pref[q].w > 0.5f) << bit;
    }
    // ---- Issue next batch's loads NOW; in flight across all of batch m ----
    if (m == 0) {
      #pragma unroll
      for (int q = 0; q < 8; ++q)
        pref[q] = E4[base0 + 2048 + w * 512 + q * 64 + lane];
    }
    mA |= (unsigned)__shfl_xor((int)mA, 32);
    mB |= (unsigned)__shfl_xor((int)mB, 32);
    if (lane < 32) {
      sl[w][2 * lane]     = (unsigned short)mA;
      sl[w][2 * lane + 1] = (unsigned short)mB;
    }
    __syncthreads();                                    // B1

    // ---- Assemble full row masks (col mask == row mask; A symmetric) ----
    if (tid < 128) {
      const int c = tid >> 1, hf = tid & 1;
      const unsigned v = (unsigned)sl[2 * hf][c] | ((unsigned)sl[2 * hf + 1][c] << 16);
      if (hf == 0) rms[c].x = v; else rms[c].y = v;
    }
    __syncthreads();                                    // B2

    const int rp_r = 16 * w + (lane >> 2);   // row-pass: 4 lanes per row
    const int rp_q = lane & 3;
    const float m_r = nmask[b * NN + rp_r];

    write_A(bufA, rms[lane], w, lane);
    __syncthreads();                                    // B3

    // ---- m1: k2 tile (R,C); Bf hoisted for reuse in m2 ----
    bf16x8 Bf[4];
    #pragma unroll
    for (int K = 0; K < 4; ++K) Bf[K] = frag_ld(bufA, C * 32 + c31, 2 * K + h);
    f32x16 acc;
    #pragma unroll
    for (int r = 0; r < 16; ++r) acc[r] = 0.f;
    #pragma unroll
    for (int K = 0; K < 4; ++K) {
      const bf16x8 af = frag_ld(bufA, R * 32 + c31, 2 * K + h);
      acc = __builtin_amdgcn_mfma_f32_32x32x16_bf16(af, Bf[K], acc, 0, 0, 0);
    }
    pack_k2(bufK2, acc, R, C, c31, h);
    __syncthreads();                                    // B4

    // ---- m2: k3 tile (R,C) = k2[R] @ A[C] ----
    f32x16 d;
    #pragma unroll
    for (int r = 0; r < 16; ++r) d[r] = 0.f;
    #pragma unroll
    for (int K = 0; K < 4; ++K) {
      const bf16x8 kf = frag_ld(bufK2, R * 32 + c31, 2 * K + h);
      d = __builtin_amdgcn_mfma_f32_32x32x16_bf16(kf, Bf[K], d, 0, 0, 0);
    }
    diag_c3(c3sh, d, R, C, c31, h);
    pack_k3(bufA, d, R, C, c31, h);   // all bufA reads (Bf/af) happened pre-B4
    __syncthreads();                                    // B5

    // ---- Row-pass + 2-level quarter-lane butterfly ----
    const uint2 mr = rms[rp_r];
    RP r = rowpass(bufK2, bufA, c3sh, mr, rp_r, rp_q);
    #pragma unroll
    for (int off = 1; off <= 2; off <<= 1) {
      r.diag4 += __shfl_xor(r.diag4, off);
      r.Ad    += __shfl_xor(r.Ad, off);
      r.diag5 += __shfl_xor(r.diag5, off);
      r.t3p   += __shfl_xor(r.t3p, off);
      r.Atri  += __shfl_xor(r.Atri, off);
      r.t1p   += __shfl_xor(r.t1p, off);
      r.t8p   += __shfl_xor(r.t8p, off);
    }

    const float di  = (float)(__popc(mr.x) + __popc(mr.y));
    const float c3i = c3sh[rp_r];
    const float c4 = r.diag4 - di * (di - 1.f) - r.Ad;
    const float c5 = r.diag5 - 2.f * c3i * di - r.Atri + c3i;
    const float c6p = r.t1p + 3.f * r.t8p
              - 3.f * (c3i * c3i)
              + 9.f * r.t3p
              - 6.f * (di * r.diag4)
              + 6.f * r.diag4
              - 4.f * c3i
              + 4.f * (di * di * di)
              - 12.f * (di * di)
              + 4.f * di;

    if (rp_q == 0) {
      float* xo = out + ((size_t)b * NN + rp_r) * 3;
      xo[0] = fminf(c3i * 0.05f * m_r, 1.f);
      xo[1] = fminf(c4  * 0.05f * m_r, 1.f);
      xo[2] = fminf(c5  * 0.05f * m_r, 1.f);
    }

    float sc3 = c3i, sc4 = c4, sc5 = c5, sc6 = c6p;
    #pragma unroll
    for (int off = 4; off < 64; off <<= 1) {  // lanes l,l+4,... = 16 distinct rows
      sc3 += __shfl_xor(sc3, off);
      sc4 += __shfl_xor(sc4, off);
      sc5 += __shfl_xor(sc5, off);
      sc6 += __shfl_xor(sc6, off);
    }
    if (lane == 0) gpart[w] = make_float4(sc3, sc4, sc5, sc6);
    __syncthreads();                                    // B6

    if (tid == 0) {
      const float4 g0 = gpart[0], g1 = gpart[1], g2 = gpart[2], g3 = gpart[3];
      float4 y;
      y.x = fminf((g0.x + g1.x + g2.x + g3.x) * (1.f / 6.f)  * 0.1f, 1.f);
      y.y = fminf((g0.y + g1.y + g2.y + g3.y) * (1.f / 8.f)  * 0.1f, 1.f);
      y.z = fminf((g0.z + g1.z + g2.z + g3.z) * (1.f / 10.f) * 0.1f, 1.f);
      y.w = fminf((g0.w + g1.w + g2.w + g3.w) * (1.f / 12.f) * 0.1f, 1.f);
      *reinterpret_cast<float4*>(out + (size_t)BATCH * NN * 3 + b * 4) = y;
    }
  }
}

extern "C" void kernel_launch(void* const* d_in, const int* in_sizes, int n_in,
                              void* d_out, int out_size, void* d_ws, size_t ws_size,
                              hipStream_t stream) {
  const float4* E4 = reinterpret_cast<const float4*>(d_in[0]);
  const float* nmask = reinterpret_cast<const float*>(d_in[1]);
  float* out = reinterpret_cast<float*>(d_out);
  node_cycle_kernel<<<BATCH / 2, 256, 0, stream>>>(E4, nmask, out);
}

// Round 15
// 18.771 us; speedup vs baseline: 1.3046x; 1.3046x over previous
//
#include <hip/hip_runtime.h>

// NodeCycleFeatures via MFMA, 4 waves/batch, full-occupancy variant (R10 revert).
// B=2048, N=64, A = E[...,1] symmetric 0/1, zero diag.
// Wave w owns MFMA tile (R,C)=(w>>1,w&1) of k2=A@A and k3=k2@A
// (v_mfma_f32_32x32x16_bf16; all values integer-exact in bf16/u16/f32).
// C/D layout (verified R8-R14): col=lane&31, row=(reg&3)+8*(reg>>2)+4*(lane>>5).
// k2/k3 stored col-major (== row-major by symmetry), 16B-block XOR swizzle.
// Row-pass: wave w owns ROWS [16w,16w+16), 4 lanes/row; partials merged by
// 2-level shfl butterfly. LDS ~17.7KB; grid 2048 -> 8 blocks/CU co-resident.
// R11-R14 ledger: all halved-grid / split / serial-ballot variants regressed;
// TLP across 8 small blocks/CU beats any intra-block prefetch scheme here.

typedef __attribute__((ext_vector_type(8))) short bf16x8;
typedef __attribute__((ext_vector_type(16))) float f32x16;

constexpr int BATCH = 2048;
constexpr int NN = 64;

__device__ __forceinline__ bf16x8 frag_ld(const unsigned short* buf, int row, int kb2) {
  const int idx = row * 64 + ((kb2 ^ (row & 7)) << 3);  // 16B-block swizzle
  const uint4 v = *reinterpret_cast<const uint4*>(buf + idx);
  union { uint4 u; bf16x8 b; } cv; cv.u = v; return cv.b;
}

__global__ __launch_bounds__(256, 8) void node_cycle_kernel(
    const float4* __restrict__ E4,   // [B,N,N,2] floats viewed as float4
    const float* __restrict__ nmask, // [B,N]
    float* __restrict__ out)         // x: [B,N,3] then y: [B,4]
{
  const int b = blockIdx.x;
  const int tid = threadIdx.x;
  const int lane = tid & 63;
  const int w = tid >> 6;            // wave id 0..3
  const int h = lane >> 5;           // lane half (MFMA k-half)
  const int c31 = lane & 31;
  const int R = w >> 1, C = w & 1;   // this wave's MFMA tile

  __shared__ unsigned short bufA[64 * 64];   // A bf16; reused for k3 (u16)
  __shared__ unsigned short bufK2[64 * 64];  // k2 bf16 (col-major == row-major)
  __shared__ unsigned short sl[4][64];       // per-wave 16-bit col-mask slices
  __shared__ uint2 rms[NN];                  // full row masks
  __shared__ float c3sh[NN];
  __shared__ float4 gpart[4];                // per-wave graph-sum partials

  const float4* __restrict__ Eb = E4 + (size_t)b * (NN * NN / 2);

  // Row-pass ownership: wave w rows [16w,16w+16), 4 lanes per row.
  const int rp_r = 16 * w + (lane >> 2);
  const int rp_q = lane & 3;
  const float m_r = nmask[b * NN + rp_r];    // early scalar global load

  // ---- Phase L: wave w loads rows [16w,16w+16) (coalesced float4), builds
  // 16-bit column-mask slices. float4 i=w*512+q*64+lane: row=16w+2q+h,
  // colpair=lane&31 (.y=col 2c, .w=col 2c+1).
  unsigned mA = 0u, mB = 0u;
  #pragma unroll
  for (int q = 0; q < 8; ++q) {
    const float4 f = Eb[w * 512 + q * 64 + lane];
    const int bit = 2 * q + h;
    mA |= (unsigned)(f.y > 0.5f) << bit;
    mB |= (unsigned)(f.w > 0.5f) << bit;
  }
  mA |= (unsigned)__shfl_xor((int)mA, 32);
  mB |= (unsigned)__shfl_xor((int)mB, 32);
  if (lane < 32) {
    sl[w][2 * lane]     = (unsigned short)mA;
    sl[w][2 * lane + 1] = (unsigned short)mB;
  }
  __syncthreads();                                    // B1

  // ---- Assemble full row masks (col mask == row mask; A symmetric) ----
  if (tid < 128) {
    const int c = tid >> 1, hf = tid & 1;
    const unsigned v = (unsigned)sl[2 * hf][c] | ((unsigned)sl[2 * hf + 1][c] << 16);
    if (hf == 0) rms[c].x = v; else rms[c].y = v;
  }
  __syncthreads();                                    // B2

  const uint2 mrL = rms[lane];

  // ---- Write A as bf16 (swizzled row-major): row=lane, col-quarter w ----
  {
    const unsigned word = (w < 2) ? mrL.x : mrL.y;
    const unsigned bits16 = (word >> (16 * (w & 1))) & 0xffffu;
    #pragma unroll
    for (int e = 0; e < 2; ++e) {
      const int bq = 2 * w + e;
      unsigned wv[4];
      #pragma unroll
      for (int p2 = 0; p2 < 4; ++p2) {
        const int c0 = e * 8 + p2 * 2;
        wv[p2] = (((bits16 >> c0) & 1u) ? 0x3F80u : 0u)
               | (((bits16 >> (c0 + 1)) & 1u) ? 0x3F800000u : 0u);
      }
      const int idx = lane * 64 + ((bq ^ (lane & 7)) << 3);
      *reinterpret_cast<uint4*>(&bufA[idx]) = make_uint4(wv[0], wv[1], wv[2], wv[3]);
    }
  }
  __syncthreads();                                    // B3

  // ---- m1: k2 tile (R,C). Bf hoisted (reused by m2); Af staged per-K ----
  bf16x8 Bf[4];
  #pragma unroll
  for (int K = 0; K < 4; ++K) Bf[K] = frag_ld(bufA, C * 32 + c31, 2 * K + h);

  f32x16 acc;
  #pragma unroll
  for (int r = 0; r < 16; ++r) acc[r] = 0.f;
  #pragma unroll
  for (int K = 0; K < 4; ++K) {
    const bf16x8 af = frag_ld(bufA, R * 32 + c31, 2 * K + h);
    acc = __builtin_amdgcn_mfma_f32_32x32x16_bf16(af, Bf[K], acc, 0, 0, 0);
  }

  // ---- Pack k2 tile -> bufK2 col-major bf16 (regs 4g..4g+3 = 4 rows) ----
  {
    const int c = C * 32 + c31;
    #pragma unroll
    for (int g = 0; g < 4; ++g) {
      const unsigned w0 = (__float_as_uint(acc[4*g+1]) & 0xffff0000u) |
                          (__float_as_uint(acc[4*g+0]) >> 16);
      const unsigned w1 = (__float_as_uint(acc[4*g+3]) & 0xffff0000u) |
                          (__float_as_uint(acc[4*g+2]) >> 16);
      const int bb = (4 * R + g) ^ (c & 7);
      *reinterpret_cast<uint2*>(&bufK2[c * 64 + bb * 8 + h * 4]) = make_uint2(w0, w1);
    }
  }
  __syncthreads();                                    // B4

  // ---- m2: k3 tile (R,C) = k2[R] @ A[C] (Kf staged per-K, Bf in regs) ----
  f32x16 d;
  #pragma unroll
  for (int r = 0; r < 16; ++r) d[r] = 0.f;
  #pragma unroll
  for (int K = 0; K < 4; ++K) {
    const bf16x8 kf = frag_ld(bufK2, R * 32 + c31, 2 * K + h);
    d = __builtin_amdgcn_mfma_f32_32x32x16_bf16(kf, Bf[K], d, 0, 0, 0);
  }

  // ---- c3 = diag(k3): diagonal tiles only ----
  if (R == C) {
    const int dtarget = c31 - 4 * h;
    float c3d = 0.f;
    #pragma unroll
    for (int r = 0; r < 16; ++r) {
      const int rowbase = (r & 3) + 8 * (r >> 2);
      c3d += (rowbase == dtarget) ? d[r] : 0.f;
    }
    if (((c31 >> 2) & 1) == h) c3sh[R * 32 + c31] = c3d;
  }

  // ---- Pack k3 tile -> bufA as u16 (k3 <= 3844 exact; all bufA reads done) ----
  {
    const int c = C * 32 + c31;
    #pragma unroll
    for (int g = 0; g < 4; ++g) {
      const unsigned u0 = ((unsigned)d[4*g+0]) | (((unsigned)d[4*g+1]) << 16);
      const unsigned u1 = ((unsigned)d[4*g+2]) | (((unsigned)d[4*g+3]) << 16);
      const int bb = (4 * R + g) ^ (c & 7);
      *reinterpret_cast<uint2*>(&bufA[c * 64 + bb * 8 + h * 4]) = make_uint2(u0, u1);
    }
  }
  __syncthreads();                                    // B5

  // ---- Row-pass: lane -> (row rp_r, col-quarter rp_q), 16 cols/lane ----
  const uint2 mr = rms[rp_r];                         // 4-lane broadcast
  float diag4 = 0.f, Ad = 0.f, diag5 = 0.f, t3p = 0.f, Atri = 0.f;
  float t1p = 0.f, t8p = 0.f;
  #pragma unroll
  for (int e = 0; e < 2; ++e) {
    const int bq = 2 * rp_q + e;
    const int idx = rp_r * 64 + ((bq ^ (rp_r & 7)) << 3);
    const uint4 vk2 = *reinterpret_cast<const uint4*>(&bufK2[idx]);
    const uint4 vk3 = *reinterpret_cast<const uint4*>(&bufA[idx]);
    const float4 c3a = *reinterpret_cast<const float4*>(&c3sh[bq * 8]);
    const float4 c3b = *reinterpret_cast<const float4*>(&c3sh[bq * 8 + 4]);
    const unsigned wk2[4] = {vk2.x, vk2.y, vk2.z, vk2.w};
    const unsigned wk3[4] = {vk3.x, vk3.y, vk3.z, vk3.w};
    const float c3v[8] = {c3a.x, c3a.y, c3a.z, c3a.w, c3b.x, c3b.y, c3b.z, c3b.w};
    #pragma unroll
    for (int e2 = 0; e2 < 4; ++e2) {
      const int j0 = bq * 8 + 2 * e2;
      const float k2lo = __uint_as_float(wk2[e2] << 16);
      const float k2hi = __uint_as_float(wk2[e2] & 0xffff0000u);
      const float k3lo = (float)(wk3[e2] & 0xffffu);
      const float k3hi = (float)(wk3[e2] >> 16);
      diag4 = fmaf(k2lo, k2lo, fmaf(k2hi, k2hi, diag4));
      Ad += k2lo + k2hi;                              // (A@d)[r] = row-sum of k2
      diag5 = fmaf(k2lo, k3lo, fmaf(k2hi, k3hi, diag5));
      t1p = fmaf(k3lo, k3lo, fmaf(k3hi, k3hi, t1p));  // -> trace(k6)
      t8p += k3lo + k3hi;                             // -> sum(k3)
      const unsigned b0 = (j0 < 32 ? (mr.x >> j0) : (mr.y >> (j0 - 32))) & 1u;
      const unsigned b1 = ((j0 + 1) < 32 ? (mr.x >> (j0 + 1)) : (mr.y >> (j0 + 1 - 32))) & 1u;
      t3p = fmaf(b0 ? k2lo : 0.f, k2lo, fmaf(b1 ? k2hi : 0.f, k2hi, t3p));
      Atri += (b0 ? c3v[2 * e2] : 0.f) + (b1 ? c3v[2 * e2 + 1] : 0.f);
    }
  }
  // 2-level butterfly over the 4 quarter-lanes of each row
  #pragma unroll
  for (int off = 1; off <= 2; off <<= 1) {
    diag4 += __shfl_xor(diag4, off);
    Ad    += __shfl_xor(Ad, off);
    diag5 += __shfl_xor(diag5, off);
    t3p   += __shfl_xor(t3p, off);
    Atri  += __shfl_xor(Atri, off);
    t1p   += __shfl_xor(t1p, off);
    t8p   += __shfl_xor(t8p, off);
  }

  // ---- Per-row quantities (all 4 lanes of a row hold full-row values) ----
  const float di  = (float)(__popc(mr.x) + __popc(mr.y));
  const float c3i = c3sh[rp_r];
  const float c4 = diag4 - di * (di - 1.f) - Ad;
  const float c5 = diag5 - 2.f * c3i * di - Atri + c3i;
  const float c6p = t1p + 3.f * t8p
            - 3.f * (c3i * c3i)
            + 9.f * t3p
            - 6.f * (di * diag4)
            + 6.f * diag4
            - 4.f * c3i
            + 4.f * (di * di * di)
            - 12.f * (di * di)
            + 4.f * di;

  // ---- x outputs: one lane per row ----
  if (rp_q == 0) {
    float* xo = out + ((size_t)b * NN + rp_r) * 3;
    xo[0] = fminf(c3i * 0.05f * m_r, 1.f);
    xo[1] = fminf(c4  * 0.05f * m_r, 1.f);
    xo[2] = fminf(c5  * 0.05f * m_r, 1.f);
  }

  // ---- Graph sums: lanes l, l+4, ..., l+60 are 16 distinct rows ----
  float sc3 = c3i, sc4 = c4, sc5 = c5, sc6 = c6p;
  #pragma unroll
  for (int off = 4; off < 64; off <<= 1) {
    sc3 += __shfl_xor(sc3, off);
    sc4 += __shfl_xor(sc4, off);
    sc5 += __shfl_xor(sc5, off);
    sc6 += __shfl_xor(sc6, off);
  }
  if (lane == 0) gpart[w] = make_float4(sc3, sc4, sc5, sc6);
  __syncthreads();                                    // B6

  if (tid == 0) {
    const float4 g0 = gpart[0], g1 = gpart[1], g2 = gpart[2], g3 = gpart[3];
    float4 y;
    y.x = fminf((g0.x + g1.x + g2.x + g3.x) * (1.f / 6.f)  * 0.1f, 1.f);
    y.y = fminf((g0.y + g1.y + g2.y + g3.y) * (1.f / 8.f)  * 0.1f, 1.f);
    y.z = fminf((g0.z + g1.z + g2.z + g3.z) * (1.f / 10.f) * 0.1f, 1.f);
    y.w = fminf((g0.w + g1.w + g2.w + g3.w) * (1.f / 12.f) * 0.1f, 1.f);
    *reinterpret_cast<float4*>(out + (size_t)BATCH * NN * 3 + b * 4) = y;
  }
}

extern "C" void kernel_launch(void* const* d_in, const int* in_sizes, int n_in,
                              void* d_out, int out_size, void* d_ws, size_t ws_size,
                              hipStream_t stream) {
  const float4* E4 = reinterpret_cast<const float4*>(d_in[0]);
  const float* nmask = reinterpret_cast<const float*>(d_in[1]);
  float* out = reinterpret_cast<float*>(d_out);
  node_cycle_kernel<<<BATCH, 256, 0, stream>>>(E4, nmask, out);
}

// Round 16
// 18.606 us; speedup vs baseline: 1.3162x; 1.0088x over previous
//
#include <hip/hip_runtime.h>

// NodeCycleFeatures via MFMA, 4 waves/batch (R10 core) + short front-end.
// B=2048, N=64, A = E[...,1] symmetric 0/1, zero diag.
// Phase L writes A-bf16 DIRECTLY into LDS from the loaded floats
// (bf16(A) = top 16 bits of f32; 0.0/1.0 exact), while building mask slices.
// m1 starts after ONE barrier; mask assembly rides in the MFMA shadow.
// Wave w owns MFMA tile (R,C)=(w>>1,w&1) of k2=A@A and k3=k2@A
// (v_mfma_f32_32x32x16_bf16; all values integer-exact in bf16/u16/f32).
// C/D layout (verified R8-R15): col=lane&31, row=(reg&3)+8*(reg>>2)+4*(lane>>5).
// k2/k3 stored col-major (== row-major by symmetry), 16B-block XOR swizzle.
// 4 barriers total (was 6). Row-pass/epilogue identical to R10 (verified).

typedef __attribute__((ext_vector_type(8))) short bf16x8;
typedef __attribute__((ext_vector_type(16))) float f32x16;

constexpr int BATCH = 2048;
constexpr int NN = 64;

__device__ __forceinline__ bf16x8 frag_ld(const unsigned short* buf, int row, int kb2) {
  const int idx = row * 64 + ((kb2 ^ (row & 7)) << 3);  // 16B-block swizzle
  const uint4 v = *reinterpret_cast<const uint4*>(buf + idx);
  union { uint4 u; bf16x8 b; } cv; cv.u = v; return cv.b;
}

__global__ __launch_bounds__(256, 8) void node_cycle_kernel(
    const float4* __restrict__ E4,   // [B,N,N,2] floats viewed as float4
    const float* __restrict__ nmask, // [B,N]
    float* __restrict__ out)         // x: [B,N,3] then y: [B,4]
{
  const int b = blockIdx.x;
  const int tid = threadIdx.x;
  const int lane = tid & 63;
  const int w = tid >> 6;            // wave id 0..3
  const int h = lane >> 5;           // lane half (MFMA k-half)
  const int c31 = lane & 31;
  const int R = w >> 1, C = w & 1;   // this wave's MFMA tile

  __shared__ unsigned short bufA[64 * 64];   // A bf16; reused for k3 (u16)
  __shared__ unsigned short bufK2[64 * 64];  // k2 bf16 (col-major == row-major)
  __shared__ unsigned short sl[4][64];       // per-wave 16-bit col-mask slices
  __shared__ uint2 rms[NN];                  // full row masks
  __shared__ float c3sh[NN];
  __shared__ float4 gpart[4];                // per-wave graph-sum partials

  const float4* __restrict__ Eb = E4 + (size_t)b * (NN * NN / 2);

  // Row-pass ownership: wave w rows [16w,16w+16), 4 lanes per row.
  const int rp_r = 16 * w + (lane >> 2);
  const int rp_q = lane & 3;
  const float m_r = nmask[b * NN + rp_r];    // early scalar global load

  // ---- Phase L: load rows [16w,16w+16); write A-bf16 directly (swizzled) and
  // build 16-bit column-mask slices. float4 i=w*512+q*64+lane: row=16w+2q+h,
  // cols 2*c31 (.y) and 2*c31+1 (.w). bf16 = top half of f32 (0/1 exact).
  const int cb = c31 >> 2;          // 16B block index (8 cols/block)
  const int co = (c31 & 3) * 2;     // u16 offset within block
  unsigned mA = 0u, mB = 0u;
  #pragma unroll
  for (int q = 0; q < 8; ++q) {
    const float4 f = Eb[w * 512 + q * 64 + lane];
    const int row = 16 * w + 2 * q + h;
    const unsigned word = (__float_as_uint(f.y) >> 16) |
                          (__float_as_uint(f.w) & 0xFFFF0000u);
    *reinterpret_cast<unsigned*>(
        &bufA[row * 64 + ((cb ^ (row & 7)) << 3) + co]) = word;
    const int bit = 2 * q + h;
    mA |= (unsigned)(f.y > 0.5f) << bit;
    mB |= (unsigned)(f.w > 0.5f) << bit;
  }
  mA |= (unsigned)__shfl_xor((int)mA, 32);
  mB |= (unsigned)__shfl_xor((int)mB, 32);
  if (lane < 32) {
    sl[w][2 * lane]     = (unsigned short)mA;
    sl[w][2 * lane + 1] = (unsigned short)mB;
  }
  __syncthreads();                                    // B1: A + slices ready

  // ---- Mask assembly rides in the MFMA shadow (first read is post-B3) ----
  if (tid < 128) {
    const int c = tid >> 1, hf = tid & 1;
    const unsigned v = (unsigned)sl[2 * hf][c] | ((unsigned)sl[2 * hf + 1][c] << 16);
    if (hf == 0) rms[c].x = v; else rms[c].y = v;
  }

  // ---- m1: k2 tile (R,C). Bf hoisted (reused by m2); Af staged per-K ----
  bf16x8 Bf[4];
  #pragma unroll
  for (int K = 0; K < 4; ++K) Bf[K] = frag_ld(bufA, C * 32 + c31, 2 * K + h);

  f32x16 acc;
  #pragma unroll
  for (int r = 0; r < 16; ++r) acc[r] = 0.f;
  #pragma unroll
  for (int K = 0; K < 4; ++K) {
    const bf16x8 af = frag_ld(bufA, R * 32 + c31, 2 * K + h);
    acc = __builtin_amdgcn_mfma_f32_32x32x16_bf16(af, Bf[K], acc, 0, 0, 0);
  }

  // ---- Pack k2 tile -> bufK2 col-major bf16 (regs 4g..4g+3 = 4 rows) ----
  {
    const int c = C * 32 + c31;
    #pragma unroll
    for (int g = 0; g < 4; ++g) {
      const unsigned w0 = (__float_as_uint(acc[4*g+1]) & 0xffff0000u) |
                          (__float_as_uint(acc[4*g+0]) >> 16);
      const unsigned w1 = (__float_as_uint(acc[4*g+3]) & 0xffff0000u) |
                          (__float_as_uint(acc[4*g+2]) >> 16);
      const int bb = (4 * R + g) ^ (c & 7);
      *reinterpret_cast<uint2*>(&bufK2[c * 64 + bb * 8 + h * 4]) = make_uint2(w0, w1);
    }
  }
  __syncthreads();                                    // B2: k2 ready, bufA reads done

  // ---- m2: k3 tile (R,C) = k2[R] @ A[C] (Kf staged per-K, Bf in regs) ----
  f32x16 d;
  #pragma unroll
  for (int r = 0; r < 16; ++r) d[r] = 0.f;
  #pragma unroll
  for (int K = 0; K < 4; ++K) {
    const bf16x8 kf = frag_ld(bufK2, R * 32 + c31, 2 * K + h);
    d = __builtin_amdgcn_mfma_f32_32x32x16_bf16(kf, Bf[K], d, 0, 0, 0);
  }

  // ---- c3 = diag(k3): diagonal tiles only ----
  if (R == C) {
    const int dtarget = c31 - 4 * h;
    float c3d = 0.f;
    #pragma unroll
    for (int r = 0; r < 16; ++r) {
      const int rowbase = (r & 3) + 8 * (r >> 2);
      c3d += (rowbase == dtarget) ? d[r] : 0.f;
    }
    if (((c31 >> 2) & 1) == h) c3sh[R * 32 + c31] = c3d;
  }

  // ---- Pack k3 tile -> bufA as u16 (k3 <= 3844 exact; no bufA reads post-B2) ----
  {
    const int c = C * 32 + c31;
    #pragma unroll
    for (int g = 0; g < 4; ++g) {
      const unsigned u0 = ((unsigned)d[4*g+0]) | (((unsigned)d[4*g+1]) << 16);
      const unsigned u1 = ((unsigned)d[4*g+2]) | (((unsigned)d[4*g+3]) << 16);
      const int bb = (4 * R + g) ^ (c & 7);
      *reinterpret_cast<uint2*>(&bufA[c * 64 + bb * 8 + h * 4]) = make_uint2(u0, u1);
    }
  }
  __syncthreads();                                    // B3: k3 + c3 + rms ready

  // ---- Row-pass: lane -> (row rp_r, col-quarter rp_q), 16 cols/lane ----
  const uint2 mr = rms[rp_r];                         // 4-lane broadcast
  float diag4 = 0.f, Ad = 0.f, diag5 = 0.f, t3p = 0.f, Atri = 0.f;
  float t1p = 0.f, t8p = 0.f;
  #pragma unroll
  for (int e = 0; e < 2; ++e) {
    const int bq = 2 * rp_q + e;
    const int idx = rp_r * 64 + ((bq ^ (rp_r & 7)) << 3);
    const uint4 vk2 = *reinterpret_cast<const uint4*>(&bufK2[idx]);
    const uint4 vk3 = *reinterpret_cast<const uint4*>(&bufA[idx]);
    const float4 c3a = *reinterpret_cast<const float4*>(&c3sh[bq * 8]);
    const float4 c3b = *reinterpret_cast<const float4*>(&c3sh[bq * 8 + 4]);
    const unsigned wk2[4] = {vk2.x, vk2.y, vk2.z, vk2.w};
    const unsigned wk3[4] = {vk3.x, vk3.y, vk3.z, vk3.w};
    const float c3v[8] = {c3a.x, c3a.y, c3a.z, c3a.w, c3b.x, c3b.y, c3b.z, c3b.w};
    #pragma unroll
    for (int e2 = 0; e2 < 4; ++e2) {
      const int j0 = bq * 8 + 2 * e2;
      const float k2lo = __uint_as_float(wk2[e2] << 16);
      const float k2hi = __uint_as_float(wk2[e2] & 0xffff0000u);
      const float k3lo = (float)(wk3[e2] & 0xffffu);
      const float k3hi = (float)(wk3[e2] >> 16);
      diag4 = fmaf(k2lo, k2lo, fmaf(k2hi, k2hi, diag4));
      Ad += k2lo + k2hi;                              // (A@d)[r] = row-sum of k2
      diag5 = fmaf(k2lo, k3lo, fmaf(k2hi, k3hi, diag5));
      t1p = fmaf(k3lo, k3lo, fmaf(k3hi, k3hi, t1p));  // -> trace(k6)
      t8p += k3lo + k3hi;                             // -> sum(k3)
      const unsigned b0 = (j0 < 32 ? (mr.x >> j0) : (mr.y >> (j0 - 32))) & 1u;
      const unsigned b1 = ((j0 + 1) < 32 ? (mr.x >> (j0 + 1)) : (mr.y >> (j0 + 1 - 32))) & 1u;
      t3p = fmaf(b0 ? k2lo : 0.f, k2lo, fmaf(b1 ? k2hi : 0.f, k2hi, t3p));
      Atri += (b0 ? c3v[2 * e2] : 0.f) + (b1 ? c3v[2 * e2 + 1] : 0.f);
    }
  }
  // 2-level butterfly over the 4 quarter-lanes of each row
  #pragma unroll
  for (int off = 1; off <= 2; off <<= 1) {
    diag4 += __shfl_xor(diag4, off);
    Ad    += __shfl_xor(Ad, off);
    diag5 += __shfl_xor(diag5, off);
    t3p   += __shfl_xor(t3p, off);
    Atri  += __shfl_xor(Atri, off);
    t1p   += __shfl_xor(t1p, off);
    t8p   += __shfl_xor(t8p, off);
  }

  // ---- Per-row quantities (all 4 lanes of a row hold full-row values) ----
  const float di  = (float)(__popc(mr.x) + __popc(mr.y));
  const float c3i = c3sh[rp_r];
  const float c4 = diag4 - di * (di - 1.f) - Ad;
  const float c5 = diag5 - 2.f * c3i * di - Atri + c3i;
  const float c6p = t1p + 3.f * t8p
            - 3.f * (c3i * c3i)
            + 9.f * t3p
            - 6.f * (di * diag4)
            + 6.f * diag4
            - 4.f * c3i
            + 4.f * (di * di * di)
            - 12.f * (di * di)
            + 4.f * di;

  // ---- x outputs: one lane per row ----
  if (rp_q == 0) {
    float* xo = out + ((size_t)b * NN + rp_r) * 3;
    xo[0] = fminf(c3i * 0.05f * m_r, 1.f);
    xo[1] = fminf(c4  * 0.05f * m_r, 1.f);
    xo[2] = fminf(c5  * 0.05f * m_r, 1.f);
  }

  // ---- Graph sums: lanes l, l+4, ..., l+60 are 16 distinct rows ----
  float sc3 = c3i, sc4 = c4, sc5 = c5, sc6 = c6p;
  #pragma unroll
  for (int off = 4; off < 64; off <<= 1) {
    sc3 += __shfl_xor(sc3, off);
    sc4 += __shfl_xor(sc4, off);
    sc5 += __shfl_xor(sc5, off);
    sc6 += __shfl_xor(sc6, off);
  }
  if (lane == 0) gpart[w] = make_float4(sc3, sc4, sc5, sc6);
  __syncthreads();                                    // B4

  if (tid == 0) {
    const float4 g0 = gpart[0], g1 = gpart[1], g2 = gpart[2], g3 = gpart[3];
    float4 y;
    y.x = fminf((g0.x + g1.x + g2.x + g3.x) * (1.f / 6.f)  * 0.1f, 1.f);
    y.y = fminf((g0.y + g1.y + g2.y + g3.y) * (1.f / 8.f)  * 0.1f, 1.f);
    y.z = fminf((g0.z + g1.z + g2.z + g3.z) * (1.f / 10.f) * 0.1f, 1.f);
    y.w = fminf((g0.w + g1.w + g2.w + g3.w) * (1.f / 12.f) * 0.1f, 1.f);
    *reinterpret_cast<float4*>(out + (size_t)BATCH * NN * 3 + b * 4) = y;
  }
}

extern "C" void kernel_launch(void* const* d_in, const int* in_sizes, int n_in,
                              void* d_out, int out_size, void* d_ws, size_t ws_size,
                              hipStream_t stream) {
  const float4* E4 = reinterpret_cast<const float4*>(d_in[0]);
  const float* nmask = reinterpret_cast<const float*>(d_in[1]);
  float* out = reinterpret_cast<float*>(d_out);
  node_cycle_kernel<<<BATCH, 256, 0, stream>>>(E4, nmask, out);
}